// Round 9
// baseline (725.962 us; speedup 1.0000x reference)
//
#include <hip/hip_runtime.h>

#define BB 512
#define TT 512
#define KK 9
#define VP1 30001   // V+1 rows in emb
#define BTK ((size_t)BB * TT * KK)

typedef __attribute__((ext_vector_type(8))) short short8;
typedef __attribute__((ext_vector_type(4))) float float4v;

__device__ __forceinline__ float sigm(float x) {
    return __builtin_amdgcn_rcpf(1.0f + __expf(-x));
}
__device__ __forceinline__ float tanh_(float x) {
    return 1.0f - 2.0f * __builtin_amdgcn_rcpf(__expf(2.0f * x) + 1.0f);
}

__device__ __forceinline__ unsigned short f2bf(float f) {
    unsigned int u = __float_as_uint(f);
    unsigned int r = u + 0x7fffu + ((u >> 16) & 1u);
    return (unsigned short)(r >> 16);
}
__device__ __forceinline__ float bflo2f(unsigned int d) { return __uint_as_float(d << 16); }
__device__ __forceinline__ float bfhi2f(unsigned int d) { return __uint_as_float(d & 0xffff0000u); }

// broadcast lane i's float via SGPR
__device__ __forceinline__ float bcast(float v, int i) {
    return __uint_as_float(__builtin_amdgcn_readlane(__float_as_uint(v), i));
}

// barrier that does NOT drain vmcnt. 0xC07F = vmcnt(63) expcnt(7) lgkmcnt(0).
__device__ __forceinline__ void block_sync_lds() {
    __builtin_amdgcn_s_waitcnt(0xC07F);
    __builtin_amdgcn_s_barrier();
}

// ---------------------------------------------------------------------------
// One-time W swizzle (unchanged from R8)
// ---------------------------------------------------------------------------
__global__ __launch_bounds__(256)
void wswz_kernel(const float* __restrict__ Wf, const float* __restrict__ bfv,
                 const float* __restrict__ Wb, const float* __restrict__ bbv,
                 unsigned short* __restrict__ wswz, float* __restrict__ bsw)
{
    const int tid = threadIdx.x;
#pragma unroll
    for (int it = 0; it < 16; ++it) {
        int o = blockIdx.x * 4096 + it * 256 + tid;   // o = c*64 + k
        int k = o & 63, c = o >> 6;
        int dir = c >> 8, rem = c & 255;
        int u = rem >> 2, g = rem & 3;
        float val = (dir ? Wb : Wf)[k * 256 + g * 64 + u];
        wswz[o] = f2bf(val);
    }
    if (blockIdx.x == 0) {
#pragma unroll
        for (int h = 0; h < 2; ++h) {
            int c = h * 256 + tid;
            int dir = c >> 8, rem = c & 255;
            bsw[c] = (dir ? bbv : bfv)[(rem & 3) * 64 + (rem >> 2)];
        }
    }
}

// ---------------------------------------------------------------------------
// embW GEMM (unchanged from R8)
// ---------------------------------------------------------------------------
__global__ __launch_bounds__(256, 1)
void embw_kernel(const float* __restrict__ emb,
                 const unsigned short* __restrict__ wswz, const float* __restrict__ bsw,
                 unsigned short* __restrict__ embw)
{
    const int v0 = blockIdx.x * 64;
    const int tid = threadIdx.x;
    const int w = tid >> 6, lane = tid & 63;
    const int l16 = lane & 15, quad = lane >> 4;

    __shared__ __align__(16) unsigned short clds[64][520];

    short8 bFr[8][2];
    float biasn[8];
#pragma unroll
    for (int n = 0; n < 8; ++n) {
        int c = w * 128 + n * 16 + l16;
        biasn[n] = bsw[c];
        const unsigned short* wp = wswz + c * 64;
#pragma unroll
        for (int q = 0; q < 2; ++q)
            bFr[n][q] = *(const short8*)(wp + q * 32 + quad * 8);
    }

    short8 aFr[4][2];
#pragma unroll
    for (int mt = 0; mt < 4; ++mt) {
        int vrow = v0 + mt * 16 + l16;
        if (vrow >= VP1) vrow = VP1 - 1;
        const float* er = emb + (size_t)vrow * 64;
#pragma unroll
        for (int q = 0; q < 2; ++q) {
            const float* p = er + q * 32 + quad * 8;
            float4 x0 = *(const float4*)(p);
            float4 x1 = *(const float4*)(p + 4);
            short8 v;
            v[0] = (short)f2bf(x0.x); v[1] = (short)f2bf(x0.y);
            v[2] = (short)f2bf(x0.z); v[3] = (short)f2bf(x0.w);
            v[4] = (short)f2bf(x1.x); v[5] = (short)f2bf(x1.y);
            v[6] = (short)f2bf(x1.z); v[7] = (short)f2bf(x1.w);
            aFr[mt][q] = v;
        }
    }

    float4v acc[4][8];
#pragma unroll
    for (int mt = 0; mt < 4; ++mt)
#pragma unroll
        for (int n = 0; n < 8; ++n) {
            acc[mt][n][0] = biasn[n]; acc[mt][n][1] = biasn[n];
            acc[mt][n][2] = biasn[n]; acc[mt][n][3] = biasn[n];
        }
#pragma unroll
    for (int mt = 0; mt < 4; ++mt)
#pragma unroll
        for (int n = 0; n < 8; ++n) {
            acc[mt][n] = __builtin_amdgcn_mfma_f32_16x16x32_bf16(aFr[mt][0], bFr[n][0], acc[mt][n], 0, 0, 0);
            acc[mt][n] = __builtin_amdgcn_mfma_f32_16x16x32_bf16(aFr[mt][1], bFr[n][1], acc[mt][n], 0, 0, 0);
        }

#pragma unroll
    for (int mt = 0; mt < 4; ++mt)
#pragma unroll
        for (int n = 0; n < 8; ++n) {
            int cc = w * 128 + n * 16 + l16;
#pragma unroll
            for (int r = 0; r < 4; ++r)
                clds[mt * 16 + quad * 4 + r][cc] = f2bf(acc[mt][n][r]);
        }
    __syncthreads();

#pragma unroll
    for (int it = 0; it < 16; ++it) {
        int idx = it * 256 + tid;
        int row = idx >> 6, chunk = idx & 63;
        if (v0 + row < VP1) {
            uint4 val = *(const uint4*)&clds[row][chunk * 8];
            *(uint4*)(embw + (size_t)(v0 + row) * 512 + chunk * 8) = val;
        }
    }
}

// ---------------------------------------------------------------------------
// Recurrence: grid 1024 = 2 dirs x 512 rows, ONE row per block, 4 blocks/CU.
// All 4 quads run identical duplicate chains for the same row (rows 0,4,8,12
// of the h-tile are duplicates; odd rows stay zero -> persistent-acc intact).
// 4 co-resident blocks/CU overlap the ~1000-cyc serial step chain.
// ---------------------------------------------------------------------------
__global__ __launch_bounds__(256, 1)
void rec_kernel(const int* __restrict__ tokens,
                const unsigned short* __restrict__ embw,
                const float* __restrict__ Uf, const float* __restrict__ Ub,
                const float* __restrict__ Wd,
                float* __restrict__ potf, float* __restrict__ potb)
{
    const int blk = blockIdx.x;
    const int dir = blk >> 9;
    const int row = blk & 511;
    const int tid = threadIdx.x;
    const int lane = tid & 63;
    const int w = tid >> 6;
    const int l16 = lane & 15, quad = lane >> 4;
    const int u = w * 16 + l16;

    const float* Up = dir ? Ub : Uf;
    float* pot = dir ? potb : potf;
    const uint2* ebase = (const uint2*)embw + dir * 64 + u;

    __shared__ int tokl[TT];                           // 2 KB
    __shared__ __align__(16) unsigned short hl[2][16][72];

    for (int i = tid; i < 2 * 16 * 72; i += 256)
        ((unsigned short*)hl)[i] = 0;
    for (int i = tid; i < TT; i += 256)
        tokl[i] = tokens[row * TT + i];

    short8 bU[4][2];
#pragma unroll
    for (int g = 0; g < 4; ++g)
#pragma unroll
        for (int q = 0; q < 2; ++q) {
            short8 v;
#pragma unroll
            for (int j = 0; j < 8; ++j) {
                int k = q * 32 + quad * 8 + j;
                v[j] = (short)f2bf(Up[k * 256 + g * 64 + u]);
            }
            bU[g][q] = v;
        }
    short8 bW[2];
#pragma unroll
    for (int q = 0; q < 2; ++q) {
        short8 v;
#pragma unroll
        for (int j = 0; j < 8; ++j) {
            int k = q * 32 + quad * 8 + j;
            v[j] = (l16 < KK) ? (short)f2bf(Wd[(dir * 64 + k) * KK + l16]) : (short)0;
        }
        bW[q] = v;
    }

    __syncthreads();

    int tokA[4], tokB[4];
    uint2 zxp[4];
#pragma unroll
    for (int d = 0; d < 4; ++d) {
        int td = dir ? (TT - 1 - d) : d;
        int td4 = dir ? (TT - 1 - (d + 4)) : (d + 4);
        tokA[d] = tokl[td];
        tokB[d] = tokl[td4];
    }
#pragma unroll
    for (int d = 0; d < 4; ++d)
        zxp[d] = ebase[(size_t)tokA[d] << 7];

    float c_st = 0.f, h_st = 0.f;

    float4v accg[4];
#pragma unroll
    for (int g = 0; g < 4; ++g) {
        accg[g][0] = 0.f; accg[g][1] = 0.f; accg[g][2] = 0.f; accg[g][3] = 0.f;
    }

    const int tprev0 = dir ? (w == 0 ? TT - 4 : TT - w) : (w == 0 ? 3 : w - 1);
    int vOff = ((row * TT + tprev0) * KK + l16) * 4;
    const int vStep = (dir ? -4 : 4) * KK * 4;

    for (int sb = 0; sb < TT; sb += 4) {
#pragma unroll
        for (int ss = 0; ss < 4; ++ss) {
            const int s = sb + ss;
            int tcur = tokA[ss];
            uint2 zcur = zxp[ss];

            hl[ss & 1][quad * 4][u] = f2bf(h_st);

            if (s + 4 < TT)
                zxp[ss] = ebase[(size_t)tokB[ss] << 7];
            tokA[ss] = tokB[ss];

            block_sync_lds();

            const unsigned short* hrow = &hl[ss & 1][l16][0];
            short8 a0 = *(const short8*)(hrow + quad * 8);
            short8 a1 = *(const short8*)(hrow + 32 + quad * 8);

            if (s + 8 < TT) {
                int t8 = dir ? (TT - 1 - (s + 8)) : (s + 8);
                tokB[ss] = tokl[t8];
            }

            accg[0][0] = bflo2f(zcur.x);
            accg[1][0] = bfhi2f(zcur.x);
            accg[2][0] = bflo2f(zcur.y);
            accg[3][0] = bfhi2f(zcur.y);
#pragma unroll
            for (int g = 0; g < 4; ++g) {
                accg[g] = __builtin_amdgcn_mfma_f32_16x16x32_bf16(a0, bU[g][0], accg[g], 0, 0, 0);
                accg[g] = __builtin_amdgcn_mfma_f32_16x16x32_bf16(a1, bU[g][1], accg[g], 0, 0, 0);
            }

            if (w == ss && s > 0) {
                float4v accP = {0.f, 0.f, 0.f, 0.f};
                accP = __builtin_amdgcn_mfma_f32_16x16x32_bf16(a0, bW[0], accP, 0, 0, 0);
                accP = __builtin_amdgcn_mfma_f32_16x16x32_bf16(a1, bW[1], accP, 0, 0, 0);
                if (quad == 0 && l16 < KK)
                    *(float*)((char*)pot + vOff) = accP[0];
                vOff += vStep;
            }

            {
                float zi = accg[0][0], zf = accg[1][0], zg = accg[2][0], zo = accg[3][0];
                float cn = sigm(zf) * c_st + sigm(zi) * tanh_(zg);
                float hn = sigm(zo) * tanh_(cn);
                bool m = (tcur != 0);
                h_st = m ? hn : h_st;
                c_st = m ? cn : c_st;
            }
        }
    }

    hl[0][quad * 4][u] = f2bf(h_st);
    block_sync_lds();
    if (w == 0) {
        const unsigned short* hrow = &hl[0][l16][0];
        short8 a0 = *(const short8*)(hrow + quad * 8);
        short8 a1 = *(const short8*)(hrow + 32 + quad * 8);
        float4v accP = {0.f, 0.f, 0.f, 0.f};
        accP = __builtin_amdgcn_mfma_f32_16x16x32_bf16(a0, bW[0], accP, 0, 0, 0);
        accP = __builtin_amdgcn_mfma_f32_16x16x32_bf16(a1, bW[1], accP, 0, 0, 0);
        int tlast = dir ? 0 : (TT - 1);
        if (quad == 0 && l16 < KK)
            pot[((size_t)row * TT + tlast) * KK + l16] = accP[0];
    }
}

// ---------------------------------------------------------------------------
// Fused combine + Viterbi. pot read via depth-8 global prefetch ring (no pl
// LDS staging); readlane broadcast; max-fold + equality cascade; parallel
// backtrace.
// ---------------------------------------------------------------------------
__global__ __launch_bounds__(64)
void viterbi_kernel(const int* __restrict__ tokens,
                    const float* __restrict__ potf, const float* __restrict__ potb,
                    const float* __restrict__ bd, const float* __restrict__ trans,
                    float* __restrict__ dec_out, float* __restrict__ pot_out,
                    float* __restrict__ seq_out)
{
    const int row = blockIdx.x;
    const int lane = threadIdx.x;

    __shared__ unsigned char bpl[(TT - 1) * KK];
    __shared__ unsigned char maskl[TT + 8];  // padded
    __shared__ unsigned char segmap[64][KK];
    __shared__ unsigned char bseq[65];
    __shared__ float decl_[TT];

    if (lane < 8) maskl[TT + lane] = 0;

    int cnt = 0;
#pragma unroll
    for (int ch = 0; ch < TT / 64; ++ch) {
        int tk = tokens[row * TT + ch * 64 + lane];
        int m = (tk != 0) ? 1 : 0;
        maskl[ch * 64 + lane] = (unsigned char)m;
        cnt += m;
    }
    for (int off = 32; off > 0; off >>= 1) cnt += __shfl_down(cnt, off);
    if (lane == 0) seq_out[row] = (float)cnt;

    const size_t base = (size_t)row * (TT * KK);
    const float* pfr = potf + base;
    const float* pbr = potb + base;
    const float bdv = (lane < KK) ? bd[lane] : 0.f;

    // bulk pass: pot_out = potf + potb + bd (also warms L2 for the ring)
    {
        int r9 = lane % KK;
        for (int i = 0; i < (TT * KK) / 64; ++i) {
            int li = i * 64 + lane;
            float bdl = bcast(bdv, r9);   // r9 < 9 -> lanes 0..8 hold bd
            pot_out[base + li] = pfr[li] + pbr[li] + bdl;
            r9 = (r9 + 1 == KK) ? 0 : r9 + 1;
        }
    }

    float treg[KK];
#pragma unroll
    for (int i = 0; i < KK; ++i) treg[i] = (lane < KK) ? trans[i * KK + lane] : 0.f;

    float alpha = (lane < KK) ? (pfr[lane] + pbr[lane] + bdv) : -1e30f;

    // prefetch ring, depth 8: slot d holds pot parts for t = (ring base)+d
    float pfR[8], pbR[8];
#pragma unroll
    for (int d = 0; d < 8; ++d) {
        int idx = (1 + d) * KK + lane;
        pfR[d] = (lane < KK) ? pfr[idx] : 0.f;
        pbR[d] = (lane < KK) ? pbr[idx] : 0.f;
    }
    int mnext = maskl[1];

#pragma unroll 8
    for (int t = 1; t < TT; ++t) {
        const int d = (t - 1) & 7;
        float p = pfR[d] + pbR[d] + bdv;
        int m = mnext;
        mnext = maskl[t + 1];              // pad makes t+1==TT safe
        if (t + 8 < TT) {
            int idx = (t + 8) * KK + lane;
            pfR[d] = (lane < KK) ? pfr[idx] : 0.f;
            pbR[d] = (lane < KK) ? pbr[idx] : 0.f;
        }

        float sc[KK];
#pragma unroll
        for (int i = 0; i < KK; ++i) sc[i] = bcast(alpha, i) + treg[i];
        float b0 = fmaxf(fmaxf(fmaxf(sc[0], sc[1]), sc[2]),
                   fmaxf(fmaxf(fmaxf(sc[3], sc[4]), sc[5]),
                         fmaxf(fmaxf(sc[6], sc[7]), sc[8])));
        int i0 = 8;
#pragma unroll
        for (int i = 7; i >= 0; --i) i0 = (sc[i] == b0) ? i : i0;

        alpha = m ? (b0 + p) : alpha;
        int bpv = m ? i0 : lane;
        if (lane < KK) bpl[(t - 1) * KK + lane] = (unsigned char)bpv;
    }
    float sc[KK];
#pragma unroll
    for (int i = 0; i < KK; ++i) sc[i] = bcast(alpha, i);
    float b0 = fmaxf(fmaxf(fmaxf(sc[0], sc[1]), sc[2]),
               fmaxf(fmaxf(fmaxf(sc[3], sc[4]), sc[5]),
                     fmaxf(fmaxf(sc[6], sc[7]), sc[8])));
    int last = 8;
#pragma unroll
    for (int i = 7; i >= 0; --i) last = (sc[i] == b0) ? i : last;
    __syncthreads();

    {
        int l = lane;
#pragma unroll
        for (int x = 0; x < KK; ++x) {
            int y = x;
#pragma unroll
            for (int d = 7; d >= 0; --d) {
                int t = 8 * l + d;
                if (t < TT - 1) y = bpl[t * KK + y];
            }
            segmap[l][x] = (unsigned char)y;
        }
    }
    __syncthreads();
    if (lane == 0) {
        int cur = last;
        bseq[64] = (unsigned char)last;
        for (int l = 63; l >= 0; --l) {
            cur = segmap[l][cur];
            bseq[l] = (unsigned char)cur;
        }
    }
    __syncthreads();
    {
        int l = lane;
        int cur = bseq[l + 1];
#pragma unroll
        for (int d = 7; d >= 0; --d) {
            int t = 8 * l + d;
            if (t < TT - 1) cur = bpl[t * KK + cur];
            decl_[t] = (maskl[t] != 0) ? (float)cur : 0.f;
        }
    }
    __syncthreads();
#pragma unroll
    for (int ch = 0; ch < TT / 64; ++ch)
        dec_out[(size_t)row * TT + ch * 64 + lane] = decl_[ch * 64 + lane];
}

extern "C" void kernel_launch(void* const* d_in, const int* in_sizes, int n_in,
                              void* d_out, int out_size, void* d_ws, size_t ws_size,
                              hipStream_t stream)
{
    const int*   tokens = (const int*)d_in[0];
    const float* emb    = (const float*)d_in[1];
    const float* Wf     = (const float*)d_in[2];
    const float* Uf     = (const float*)d_in[3];
    const float* bfv    = (const float*)d_in[4];
    const float* Wb     = (const float*)d_in[5];
    const float* Ub     = (const float*)d_in[6];
    const float* bbv    = (const float*)d_in[7];
    const float* Wd     = (const float*)d_in[8];
    const float* bd     = (const float*)d_in[9];
    const float* trans  = (const float*)d_in[10];

    float* out     = (float*)d_out;
    float* dec_out = out;
    float* pot_out = out + (size_t)BB * TT;
    float* seq_out = out + (size_t)BB * TT + BTK;

    float* potf = (float*)d_ws;
    float* potb = potf + BTK;
    unsigned short* embw = (unsigned short*)(potb + BTK);
    // wswz/bsw alias potf: consumed by embw_kernel BEFORE rec_kernel writes potf
    unsigned short* wswz = (unsigned short*)potf;
    float* bsw = (float*)((char*)potf + 512 * 64 * sizeof(unsigned short));

    hipLaunchKernelGGL(wswz_kernel, dim3(8), dim3(256), 0, stream,
                       Wf, bfv, Wb, bbv, wswz, bsw);
    hipLaunchKernelGGL(embw_kernel, dim3(469), dim3(256), 0, stream,
                       emb, wswz, bsw, embw);
    hipLaunchKernelGGL(rec_kernel, dim3(1024), dim3(256), 0, stream,
                       tokens, embw, Uf, Ub, Wd, potf, potb);
    hipLaunchKernelGGL(viterbi_kernel, dim3(BB), dim3(64), 0, stream,
                       tokens, potf, potb, bd, trans, dec_out, pot_out, seq_out);
}

// Round 10
// 497.134 us; speedup vs baseline: 1.4603x; 1.4603x over previous
//
#include <hip/hip_runtime.h>

#define BB 512
#define TT 512
#define KK 9
#define VP1 30001   // V+1 rows in emb
#define BTK ((size_t)BB * TT * KK)

typedef __attribute__((ext_vector_type(8))) short short8;
typedef __attribute__((ext_vector_type(4))) float float4v;

__device__ __forceinline__ float sigm(float x) {
    return __builtin_amdgcn_rcpf(1.0f + __expf(-x));
}
__device__ __forceinline__ float tanh_(float x) {
    return 1.0f - 2.0f * __builtin_amdgcn_rcpf(__expf(2.0f * x) + 1.0f);
}

__device__ __forceinline__ unsigned short f2bf(float f) {
    unsigned int u = __float_as_uint(f);
    unsigned int r = u + 0x7fffu + ((u >> 16) & 1u);
    return (unsigned short)(r >> 16);
}
__device__ __forceinline__ float bflo2f(unsigned int d) { return __uint_as_float(d << 16); }
__device__ __forceinline__ float bfhi2f(unsigned int d) { return __uint_as_float(d & 0xffff0000u); }

__device__ __forceinline__ float bcast(float v, int i) {
    return __uint_as_float(__builtin_amdgcn_readlane(__float_as_uint(v), i));
}

// barrier that does NOT drain vmcnt. 0xC07F = vmcnt(63) expcnt(7) lgkmcnt(0).
__device__ __forceinline__ void block_sync_lds() {
    __builtin_amdgcn_s_waitcnt(0xC07F);
    __builtin_amdgcn_s_barrier();
}

// ---------------------------------------------------------------------------
// One-time W swizzle (R8)
// ---------------------------------------------------------------------------
__global__ __launch_bounds__(256)
void wswz_kernel(const float* __restrict__ Wf, const float* __restrict__ bfv,
                 const float* __restrict__ Wb, const float* __restrict__ bbv,
                 unsigned short* __restrict__ wswz, float* __restrict__ bsw)
{
    const int tid = threadIdx.x;
#pragma unroll
    for (int it = 0; it < 16; ++it) {
        int o = blockIdx.x * 4096 + it * 256 + tid;   // o = c*64 + k
        int k = o & 63, c = o >> 6;
        int dir = c >> 8, rem = c & 255;
        int u = rem >> 2, g = rem & 3;
        float val = (dir ? Wb : Wf)[k * 256 + g * 64 + u];
        wswz[o] = f2bf(val);
    }
    if (blockIdx.x == 0) {
#pragma unroll
        for (int h = 0; h < 2; ++h) {
            int c = h * 256 + tid;
            int dir = c >> 8, rem = c & 255;
            bsw[c] = (dir ? bbv : bfv)[(rem & 3) * 64 + (rem >> 2)];
        }
    }
}

// ---------------------------------------------------------------------------
// embW GEMM (R8)
// ---------------------------------------------------------------------------
__global__ __launch_bounds__(256, 1)
void embw_kernel(const float* __restrict__ emb,
                 const unsigned short* __restrict__ wswz, const float* __restrict__ bsw,
                 unsigned short* __restrict__ embw)
{
    const int v0 = blockIdx.x * 64;
    const int tid = threadIdx.x;
    const int w = tid >> 6, lane = tid & 63;
    const int l16 = lane & 15, quad = lane >> 4;

    __shared__ __align__(16) unsigned short clds[64][520];

    short8 bFr[8][2];
    float biasn[8];
#pragma unroll
    for (int n = 0; n < 8; ++n) {
        int c = w * 128 + n * 16 + l16;
        biasn[n] = bsw[c];
        const unsigned short* wp = wswz + c * 64;
#pragma unroll
        for (int q = 0; q < 2; ++q)
            bFr[n][q] = *(const short8*)(wp + q * 32 + quad * 8);
    }

    short8 aFr[4][2];
#pragma unroll
    for (int mt = 0; mt < 4; ++mt) {
        int vrow = v0 + mt * 16 + l16;
        if (vrow >= VP1) vrow = VP1 - 1;
        const float* er = emb + (size_t)vrow * 64;
#pragma unroll
        for (int q = 0; q < 2; ++q) {
            const float* p = er + q * 32 + quad * 8;
            float4 x0 = *(const float4*)(p);
            float4 x1 = *(const float4*)(p + 4);
            short8 v;
            v[0] = (short)f2bf(x0.x); v[1] = (short)f2bf(x0.y);
            v[2] = (short)f2bf(x0.z); v[3] = (short)f2bf(x0.w);
            v[4] = (short)f2bf(x1.x); v[5] = (short)f2bf(x1.y);
            v[6] = (short)f2bf(x1.z); v[7] = (short)f2bf(x1.w);
            aFr[mt][q] = v;
        }
    }

    float4v acc[4][8];
#pragma unroll
    for (int mt = 0; mt < 4; ++mt)
#pragma unroll
        for (int n = 0; n < 8; ++n) {
            acc[mt][n][0] = biasn[n]; acc[mt][n][1] = biasn[n];
            acc[mt][n][2] = biasn[n]; acc[mt][n][3] = biasn[n];
        }
#pragma unroll
    for (int mt = 0; mt < 4; ++mt)
#pragma unroll
        for (int n = 0; n < 8; ++n) {
            acc[mt][n] = __builtin_amdgcn_mfma_f32_16x16x32_bf16(aFr[mt][0], bFr[n][0], acc[mt][n], 0, 0, 0);
            acc[mt][n] = __builtin_amdgcn_mfma_f32_16x16x32_bf16(aFr[mt][1], bFr[n][1], acc[mt][n], 0, 0, 0);
        }

#pragma unroll
    for (int mt = 0; mt < 4; ++mt)
#pragma unroll
        for (int n = 0; n < 8; ++n) {
            int cc = w * 128 + n * 16 + l16;
#pragma unroll
            for (int r = 0; r < 4; ++r)
                clds[mt * 16 + quad * 4 + r][cc] = f2bf(acc[mt][n][r]);
        }
    __syncthreads();

#pragma unroll
    for (int it = 0; it < 16; ++it) {
        int idx = it * 256 + tid;
        int row = idx >> 6, chunk = idx & 63;
        if (v0 + row < VP1) {
            uint4 val = *(const uint4*)&clds[row][chunk * 8];
            *(uint4*)(embw + (size_t)(v0 + row) * 512 + chunk * 8) = val;
        }
    }
}

// ---------------------------------------------------------------------------
// Recurrence (R6/R8 control): grid 256 = 2 dirs x 128 slices of 4 rows.
// ---------------------------------------------------------------------------
__global__ __launch_bounds__(256, 1)
void rec_kernel(const int* __restrict__ tokens,
                const unsigned short* __restrict__ embw,
                const float* __restrict__ Uf, const float* __restrict__ Ub,
                const float* __restrict__ Wd,
                float* __restrict__ potf, float* __restrict__ potb)
{
    const int blk = blockIdx.x;
    const int dir = blk >> 7;
    const int row0 = (blk & 127) * 4;
    const int tid = threadIdx.x;
    const int lane = tid & 63;
    const int w = tid >> 6;
    const int l16 = lane & 15, quad = lane >> 4;
    const int u = w * 16 + l16;

    const float* Up = dir ? Ub : Uf;
    float* pot = dir ? potb : potf;
    const uint2* ebase = (const uint2*)embw + dir * 64 + u;

    __shared__ int tokl[4][TT];
    __shared__ __align__(16) unsigned short hl[2][16][72];

    for (int i = tid; i < 2 * 16 * 72; i += 256)
        ((unsigned short*)hl)[i] = 0;
    for (int i = tid; i < 4 * TT; i += 256) {
        int r = i >> 9, t = i & 511;
        tokl[r][t] = tokens[(row0 + r) * TT + t];
    }

    short8 bU[4][2];
#pragma unroll
    for (int g = 0; g < 4; ++g)
#pragma unroll
        for (int q = 0; q < 2; ++q) {
            short8 v;
#pragma unroll
            for (int j = 0; j < 8; ++j) {
                int k = q * 32 + quad * 8 + j;
                v[j] = (short)f2bf(Up[k * 256 + g * 64 + u]);
            }
            bU[g][q] = v;
        }
    short8 bW[2];
#pragma unroll
    for (int q = 0; q < 2; ++q) {
        short8 v;
#pragma unroll
        for (int j = 0; j < 8; ++j) {
            int k = q * 32 + quad * 8 + j;
            v[j] = (l16 < KK) ? (short)f2bf(Wd[(dir * 64 + k) * KK + l16]) : (short)0;
        }
        bW[q] = v;
    }

    __syncthreads();

    int tokA[4], tokB[4];
    uint2 zxp[4];
#pragma unroll
    for (int d = 0; d < 4; ++d) {
        int td = dir ? (TT - 1 - d) : d;
        int td4 = dir ? (TT - 1 - (d + 4)) : (d + 4);
        tokA[d] = tokl[quad][td];
        tokB[d] = tokl[quad][td4];
    }
#pragma unroll
    for (int d = 0; d < 4; ++d)
        zxp[d] = ebase[(size_t)tokA[d] << 7];

    float c_st = 0.f, h_st = 0.f;

    float4v accg[4];
#pragma unroll
    for (int g = 0; g < 4; ++g) {
        accg[g][0] = 0.f; accg[g][1] = 0.f; accg[g][2] = 0.f; accg[g][3] = 0.f;
    }

    const int tprev0 = dir ? (w == 0 ? TT - 4 : TT - w) : (w == 0 ? 3 : w - 1);
    int vOff = (((row0 + quad) * TT + tprev0) * KK + l16) * 4;
    const int vStep = (dir ? -4 : 4) * KK * 4;

    for (int sb = 0; sb < TT; sb += 4) {
#pragma unroll
        for (int ss = 0; ss < 4; ++ss) {
            const int s = sb + ss;
            int tcur = tokA[ss];
            uint2 zcur = zxp[ss];

            hl[ss & 1][quad * 4][u] = f2bf(h_st);

            if (s + 4 < TT)
                zxp[ss] = ebase[(size_t)tokB[ss] << 7];
            tokA[ss] = tokB[ss];

            block_sync_lds();

            const unsigned short* hrow = &hl[ss & 1][l16][0];
            short8 a0 = *(const short8*)(hrow + quad * 8);
            short8 a1 = *(const short8*)(hrow + 32 + quad * 8);

            if (s + 8 < TT) {
                int t8 = dir ? (TT - 1 - (s + 8)) : (s + 8);
                tokB[ss] = tokl[quad][t8];
            }

            accg[0][0] = bflo2f(zcur.x);
            accg[1][0] = bfhi2f(zcur.x);
            accg[2][0] = bflo2f(zcur.y);
            accg[3][0] = bfhi2f(zcur.y);
#pragma unroll
            for (int g = 0; g < 4; ++g) {
                accg[g] = __builtin_amdgcn_mfma_f32_16x16x32_bf16(a0, bU[g][0], accg[g], 0, 0, 0);
                accg[g] = __builtin_amdgcn_mfma_f32_16x16x32_bf16(a1, bU[g][1], accg[g], 0, 0, 0);
            }

            if (w == ss && s > 0) {
                float4v accP = {0.f, 0.f, 0.f, 0.f};
                accP = __builtin_amdgcn_mfma_f32_16x16x32_bf16(a0, bW[0], accP, 0, 0, 0);
                accP = __builtin_amdgcn_mfma_f32_16x16x32_bf16(a1, bW[1], accP, 0, 0, 0);
                if (l16 < KK)
                    *(float*)((char*)pot + vOff) = accP[0];
                vOff += vStep;
            }

            {
                float zi = accg[0][0], zf = accg[1][0], zg = accg[2][0], zo = accg[3][0];
                float cn = sigm(zf) * c_st + sigm(zi) * tanh_(zg);
                float hn = sigm(zo) * tanh_(cn);
                bool m = (tcur != 0);
                h_st = m ? hn : h_st;
                c_st = m ? cn : c_st;
            }
        }
    }

    hl[0][quad * 4][u] = f2bf(h_st);
    block_sync_lds();
    if (w == 0) {
        const unsigned short* hrow = &hl[0][l16][0];
        short8 a0 = *(const short8*)(hrow + quad * 8);
        short8 a1 = *(const short8*)(hrow + 32 + quad * 8);
        float4v accP = {0.f, 0.f, 0.f, 0.f};
        accP = __builtin_amdgcn_mfma_f32_16x16x32_bf16(a0, bW[0], accP, 0, 0, 0);
        accP = __builtin_amdgcn_mfma_f32_16x16x32_bf16(a1, bW[1], accP, 0, 0, 0);
        int tlast = dir ? 0 : (TT - 1);
        if (l16 < KK)
            pot[((size_t)(row0 + quad) * TT + tlast) * KK + l16] = accP[0];
    }
}

// ---------------------------------------------------------------------------
// Fused combine + Viterbi (R8 structure) with float4-batched staging:
// 18 float4 iters (loads pipeline under vmcnt) instead of 72 scalar iters;
// int4 token staging; float4 pot_out stores with incremental mod-9 bias.
// Idempotent: safe to launch twice (measurement round).
// ---------------------------------------------------------------------------
__global__ __launch_bounds__(64)
void viterbi_kernel(const int* __restrict__ tokens,
                    const float* __restrict__ potf, const float* __restrict__ potb,
                    const float* __restrict__ bd, const float* __restrict__ trans,
                    float* __restrict__ dec_out, float* __restrict__ pot_out,
                    float* __restrict__ seq_out)
{
    const int row = blockIdx.x;
    const int lane = threadIdx.x;

    __shared__ __align__(16) float pl[TT * KK + 16];   // padded
    __shared__ unsigned char bpl[(TT - 1) * KK];
    __shared__ __align__(4) unsigned char maskl[TT + 8];
    __shared__ unsigned char segmap[64][KK];
    __shared__ unsigned char bseq[65];
    __shared__ float decl_[TT];
    __shared__ float bdx[12];   // bd[j%9] for j<12

    if (lane < 12) bdx[lane] = bd[lane % KK];
    if (lane < 8) maskl[TT + lane] = 0;
    pl[TT * KK + (lane & 15)] = 0.f;

    // tokens via int4: 2 iters; mask bytes packed as uint
    int cnt = 0;
    {
        const int4* trow4 = (const int4*)(tokens + row * TT);
        unsigned int* mu = (unsigned int*)maskl;
#pragma unroll
        for (int i = 0; i < 2; ++i) {
            int4 tk = trow4[i * 64 + lane];
            unsigned int m0 = (tk.x != 0), m1 = (tk.y != 0), m2 = (tk.z != 0), m3 = (tk.w != 0);
            mu[i * 64 + lane] = m0 | (m1 << 8) | (m2 << 16) | (m3 << 24);
            cnt += (int)(m0 + m1 + m2 + m3);
        }
    }
    for (int off = 32; off > 0; off >>= 1) cnt += __shfl_down(cnt, off);
    if (lane == 0) seq_out[row] = (float)cnt;

    // staging: 18 float4 iters (pipelined loads), pl = potf+potb+bd
    {
        const size_t base4 = (size_t)row * (TT * KK / 4);
        const float4* pf4 = (const float4*)potf + base4;
        const float4* pb4 = (const float4*)potb + base4;
        float4* po4 = (float4*)pot_out + base4;
        float4* pl4 = (float4*)pl;
        int k0 = (lane * 4) % KK;          // (i*256 + lane*4) % 9, step +4 mod 9
#pragma unroll
        for (int i = 0; i < 18; ++i) {
            int li = i * 64 + lane;
            float4 a = pf4[li];
            float4 b = pb4[li];
            float4 s;
            s.x = a.x + b.x + bdx[k0];
            s.y = a.y + b.y + bdx[k0 + 1];
            s.z = a.z + b.z + bdx[k0 + 2];
            s.w = a.w + b.w + bdx[k0 + 3];
            pl4[li] = s;
            po4[li] = s;
            k0 += 4; if (k0 >= KK) k0 -= KK;
        }
    }
    __syncthreads();

    float treg[KK];
#pragma unroll
    for (int i = 0; i < KK; ++i) treg[i] = (lane < KK) ? trans[i * KK + lane] : 0.f;

    float alpha = (lane < KK) ? pl[lane] : -1e30f;
    float pnext = (lane < KK) ? pl[KK + lane] : 0.f;
    int mnext = maskl[1];
#pragma unroll 4
    for (int t = 1; t < TT; ++t) {
        float p = pnext;
        int m = mnext;
        pnext = (lane < KK) ? pl[(t + 1) * KK + lane] : 0.f;  // pad-safe
        mnext = maskl[t + 1];

        float sc[KK];
#pragma unroll
        for (int i = 0; i < KK; ++i) sc[i] = bcast(alpha, i) + treg[i];
        float b0 = fmaxf(fmaxf(fmaxf(sc[0], sc[1]), sc[2]),
                   fmaxf(fmaxf(fmaxf(sc[3], sc[4]), sc[5]),
                         fmaxf(fmaxf(sc[6], sc[7]), sc[8])));
        int i0 = 8;
#pragma unroll
        for (int i = 7; i >= 0; --i) i0 = (sc[i] == b0) ? i : i0;

        alpha = m ? (b0 + p) : alpha;
        int bpv = m ? i0 : lane;
        if (lane < KK) bpl[(t - 1) * KK + lane] = (unsigned char)bpv;
    }
    float sc[KK];
#pragma unroll
    for (int i = 0; i < KK; ++i) sc[i] = bcast(alpha, i);
    float b0 = fmaxf(fmaxf(fmaxf(sc[0], sc[1]), sc[2]),
               fmaxf(fmaxf(fmaxf(sc[3], sc[4]), sc[5]),
                     fmaxf(fmaxf(sc[6], sc[7]), sc[8])));
    int last = 8;
#pragma unroll
    for (int i = 7; i >= 0; --i) last = (sc[i] == b0) ? i : last;
    __syncthreads();

    {
        int l = lane;
#pragma unroll
        for (int x = 0; x < KK; ++x) {
            int y = x;
#pragma unroll
            for (int d = 7; d >= 0; --d) {
                int t = 8 * l + d;
                if (t < TT - 1) y = bpl[t * KK + y];
            }
            segmap[l][x] = (unsigned char)y;
        }
    }
    __syncthreads();
    if (lane == 0) {
        int cur = last;
        bseq[64] = (unsigned char)last;
        for (int l = 63; l >= 0; --l) {
            cur = segmap[l][cur];
            bseq[l] = (unsigned char)cur;
        }
    }
    __syncthreads();
    {
        int l = lane;
        int cur = bseq[l + 1];
#pragma unroll
        for (int d = 7; d >= 0; --d) {
            int t = 8 * l + d;
            if (t < TT - 1) cur = bpl[t * KK + cur];
            decl_[t] = (maskl[t] != 0) ? (float)cur : 0.f;
        }
    }
    __syncthreads();
#pragma unroll
    for (int ch = 0; ch < TT / 64; ++ch)
        dec_out[(size_t)row * TT + ch * 64 + lane] = decl_[ch * 64 + lane];
}

extern "C" void kernel_launch(void* const* d_in, const int* in_sizes, int n_in,
                              void* d_out, int out_size, void* d_ws, size_t ws_size,
                              hipStream_t stream)
{
    const int*   tokens = (const int*)d_in[0];
    const float* emb    = (const float*)d_in[1];
    const float* Wf     = (const float*)d_in[2];
    const float* Uf     = (const float*)d_in[3];
    const float* bfv    = (const float*)d_in[4];
    const float* Wb     = (const float*)d_in[5];
    const float* Ub     = (const float*)d_in[6];
    const float* bbv    = (const float*)d_in[7];
    const float* Wd     = (const float*)d_in[8];
    const float* bd     = (const float*)d_in[9];
    const float* trans  = (const float*)d_in[10];

    float* out     = (float*)d_out;
    float* dec_out = out;
    float* pot_out = out + (size_t)BB * TT;
    float* seq_out = out + (size_t)BB * TT + BTK;

    float* potf = (float*)d_ws;
    float* potb = potf + BTK;
    unsigned short* embw = (unsigned short*)(potb + BTK);
    unsigned short* wswz = (unsigned short*)potf;
    float* bsw = (float*)((char*)potf + 512 * 64 * sizeof(unsigned short));

    hipLaunchKernelGGL(wswz_kernel, dim3(8), dim3(256), 0, stream,
                       Wf, bfv, Wb, bbv, wswz, bsw);
    hipLaunchKernelGGL(embw_kernel, dim3(469), dim3(256), 0, stream,
                       emb, wswz, bsw, embw);
    hipLaunchKernelGGL(rec_kernel, dim3(256), dim3(256), 0, stream,
                       tokens, embw, Uf, Ub, Wd, potf, potb);
    // MEASUREMENT: viterbi launched twice (idempotent). total - baseline = viterbi cost.
    hipLaunchKernelGGL(viterbi_kernel, dim3(BB), dim3(64), 0, stream,
                       tokens, potf, potb, bd, trans, dec_out, pot_out, seq_out);
    hipLaunchKernelGGL(viterbi_kernel, dim3(BB), dim3(64), 0, stream,
                       tokens, potf, potb, bd, trans, dec_out, pot_out, seq_out);
}